// Round 5
// baseline (213.744 us; speedup 1.0000x reference)
//
#include <hip/hip_runtime.h>
#include <stdint.h>

// SpectralFreqTimeConv2D: B=32, N=128, C=32, M=17. Truncated-DFT factorization.
// R5: fwd_y and inv_y as MFMA bf16 GEMMs with 3-term split-bf16 (fp32-accurate).
// Mid kernel (k_mid_fused) intentionally unchanged from R4 to isolate MFMA risk.

typedef unsigned int uint32;
typedef __attribute__((ext_vector_type(8))) short short8;   // 8 bf16 (4 VGPRs)
typedef __attribute__((ext_vector_type(4))) float f32x4;

#define TWO_PI_OVER_128 0.04908738521234052f

__device__ __forceinline__ unsigned short bfhi(float v) {
    uint32 u = __float_as_uint(v);
    return (unsigned short)((u + 0x7fffu + ((u >> 16) & 1u)) >> 16);
}
__device__ __forceinline__ float bf2f(unsigned short h) {
    return __uint_as_float(((uint32)h) << 16);
}

// ---------------- K0: t1/t2 = t_emb @ (k_real, k_imag) -> tbuf[which][b][i][2]
__global__ __launch_bounds__(128) void k_tproj(
    const float* __restrict__ temb, const float* __restrict__ k1r, const float* __restrict__ k1i,
    const float* __restrict__ k2r, const float* __restrict__ k2i, float* __restrict__ tbuf)
{
    int b = blockIdx.x, tid = threadIdx.x;
    __shared__ float ts[256];
    for (int d = tid; d < 256; d += 128) ts[d] = temb[b * 256 + d];
    __syncthreads();
    if (tid < 68) {
        int which = (tid >= 34) ? 1 : 0;
        int rem = tid - which * 34;
        int i = rem >> 1, part = rem & 1;
        const float* kp = which ? (part ? k2i : k2r) : (part ? k1i : k1r);
        float acc = 0.f;
        for (int d = 0; d < 256; ++d) acc += ts[d] * kp[d * 17 + i];
        tbuf[((which * 32 + b) * 17 + i) * 2 + part] = acc;
    }
}

// ---------------- K-tab: DFT basis tables (bf16 hi/lo) in ws. Rebuilt every launch.
// D[48][128]: row 2p = cos(2pi p y/128)/16384, row 2p+1 = -sin(..)/16384, rows>=34 zero.
// E[128][32]: E[y][2j] = w_j cos(2pi j y/128), E[y][2j+1] = -w_j sin(..); w_0=1 else 2.
//             (col 1 = 0 encodes c2r's "ignore DC imag".)
// Et[128][2]: j=16 tail: 2cos(pi y/4), -2sin(pi y/4)  (fp32).
__global__ __launch_bounds__(256) void k_mktab(
    unsigned short* __restrict__ Dhi, unsigned short* __restrict__ Dlo,
    unsigned short* __restrict__ Ehi, unsigned short* __restrict__ Elo,
    float* __restrict__ Et)
{
    int tid = threadIdx.x;
    for (int i = tid; i < 48 * 128; i += 256) {
        int m = i >> 7, y = i & 127;
        float v = 0.f;
        if (m < 34) {
            int p = m >> 1;
            int k = (p * y) & 127;                       // exact period-128 reduction
            float sn, cs; sincosf(TWO_PI_OVER_128 * (float)k, &sn, &cs);
            v = ((m & 1) ? -sn : cs) * (1.f / 16384.f);  // norm='forward'
        }
        unsigned short h = bfhi(v);
        Dhi[i] = h; Dlo[i] = bfhi(v - bf2f(h));
    }
    for (int i = tid; i < 128 * 32; i += 256) {
        int y = i >> 5, q = i & 31;
        int j = q >> 1;
        int k = (j * y) & 127;
        float sn, cs; sincosf(TWO_PI_OVER_128 * (float)k, &sn, &cs);
        float w = (j == 0) ? 1.f : 2.f;
        float v = (q & 1) ? (-w * sn) : (w * cs);
        if (q == 1) v = 0.f;                             // DC imag ignored
        unsigned short h = bfhi(v);
        Ehi[i] = h; Elo[i] = bfhi(v - bf2f(h));
    }
    for (int i = tid; i < 128; i += 256) {
        int k = (16 * i) & 127;
        float sn, cs; sincosf(TWO_PI_OVER_128 * (float)k, &sn, &cs);
        Et[i * 2] = 2.f * cs; Et[i * 2 + 1] = -2.f * sn;
    }
}

// ---------------- K1 (MFMA): y-DFT. 4 waves/block, wave = one (b,x)-row, no LDS.
// T1[34 jreim rows][32 c] = D[34(pad48) x 128y] * X[128y x 32c], split-bf16 3-term.
__global__ __launch_bounds__(256) void k_fwd_y_mfma(
    const float* __restrict__ x, float2* __restrict__ T1,
    const unsigned short* __restrict__ Dhi, const unsigned short* __restrict__ Dlo)
{
    int wave = threadIdx.x >> 6, lane = threadIdx.x & 63;
    int row = (blockIdx.x << 2) + wave;                  // (b,x)-row, grid 1024
    int b = row >> 7, xr = row & 127;
    const float* xp = x + ((size_t)row << 12);           // [128y][32c]
    int col = lane & 15, quad = lane >> 4;
    f32x4 acc[3][2];
#pragma unroll
    for (int m = 0; m < 3; ++m)
#pragma unroll
        for (int n = 0; n < 2; ++n) acc[m][n] = (f32x4){0.f, 0.f, 0.f, 0.f};
#pragma unroll
    for (int t = 0; t < 4; ++t) {                        // k-tiles over y
        int y0 = t * 32 + quad * 8;
        short8 xh[2], xl[2];
#pragma unroll
        for (int n = 0; n < 2; ++n) {                    // B-frag: B[k=y][n=c]
            const float* xc = xp + (n << 4) + col;
#pragma unroll
            for (int jj = 0; jj < 8; ++jj) {
                float v = xc[(y0 + jj) << 5];
                unsigned short h = bfhi(v);
                xh[n][jj] = (short)h;
                xl[n][jj] = (short)bfhi(v - bf2f(h));
            }
        }
#pragma unroll
        for (int m = 0; m < 3; ++m) {                    // A-frag: A[m=jreim][k=y]
            int doff = (((m << 4) + col) << 7) + t * 32 + quad * 8;
            short8 dh = *(const short8*)(Dhi + doff);
            short8 dl = *(const short8*)(Dlo + doff);
#pragma unroll
            for (int n = 0; n < 2; ++n) {
                acc[m][n] = __builtin_amdgcn_mfma_f32_16x16x32_bf16(dh, xh[n], acc[m][n], 0, 0, 0);
                acc[m][n] = __builtin_amdgcn_mfma_f32_16x16x32_bf16(dh, xl[n], acc[m][n], 0, 0, 0);
                acc[m][n] = __builtin_amdgcn_mfma_f32_16x16x32_bf16(dl, xh[n], acc[m][n], 0, 0, 0);
            }
        }
    }
    // C layout: col=lane&15, row=quad*4+reg. Rows (2j,2j+1) = (re,im) of mode j.
#pragma unroll
    for (int m = 0; m < 3; ++m) {
        int j0 = (m << 3) + (quad << 1);                 // rows m*16+quad*4 -> j0, regs 2,3 -> j0+1
#pragma unroll
        for (int n = 0; n < 2; ++n) {
            int c = (n << 4) + col;
            if (m < 2 || quad == 0) {
                float2* p = T1 + (((size_t)(b * 17 + j0) * 128 + xr) << 5) + c;
                *p = make_float2(acc[m][n][0], acc[m][n][1]);
            }
            if (m < 2) {
                float2* p = T1 + (((size_t)(b * 17 + j0 + 1) * 128 + xr) << 5) + c;
                *p = make_float2(acc[m][n][2], acc[m][n][3]);
            }
        }
    }
}

// ---------------- K4 (MFMA): inverse-y c2r. wave = one (b,x)-row.
// out[128y x 32o] = E[128y x 32k] * Uv[32k x 32o] + j=16 tail (fp32 VALU).
__global__ __launch_bounds__(256) void k_inv_y_mfma(
    const float2* __restrict__ U, float* __restrict__ out,
    const unsigned short* __restrict__ Ehi, const unsigned short* __restrict__ Elo,
    const float* __restrict__ Et)
{
    int wave = threadIdx.x >> 6, lane = threadIdx.x & 63;
    int row = (blockIdx.x << 2) + wave;
    const float2* Up = U + (size_t)row * 544;            // [17 j][32 o] complex
    float* outp = out + ((size_t)row << 12);
    int col = lane & 15, quad = lane >> 4;
    // B-frags: Uv[k=2j+r][o]; k = quad*8 + idx
    short8 uh[2], ul[2];
#pragma unroll
    for (int n = 0; n < 2; ++n) {
        int o = (n << 4) + col;
#pragma unroll
        for (int m = 0; m < 4; ++m) {
            int j = (quad << 2) + m;                     // j = k>>1, 0..15
            float2 uv = Up[(j << 5) + o];
            unsigned short h0 = bfhi(uv.x);
            uh[n][2 * m]     = (short)h0;
            ul[n][2 * m]     = (short)bfhi(uv.x - bf2f(h0));
            unsigned short h1 = bfhi(uv.y);
            uh[n][2 * m + 1] = (short)h1;
            ul[n][2 * m + 1] = (short)bfhi(uv.y - bf2f(h1));
        }
    }
    float2 u16a = Up[(16 << 5) + col];                   // j=16 (fp32 tail)
    float2 u16b = Up[(16 << 5) + 16 + col];
#pragma unroll
    for (int mt = 0; mt < 8; ++mt) {
        f32x4 a0 = (f32x4){0.f, 0.f, 0.f, 0.f};
        f32x4 a1 = (f32x4){0.f, 0.f, 0.f, 0.f};
        int eoff = (((mt << 4) + col) << 5) + (quad << 3);   // A[m=y][k]
        short8 eh = *(const short8*)(Ehi + eoff);
        short8 el = *(const short8*)(Elo + eoff);
        a0 = __builtin_amdgcn_mfma_f32_16x16x32_bf16(eh, uh[0], a0, 0, 0, 0);
        a0 = __builtin_amdgcn_mfma_f32_16x16x32_bf16(eh, ul[0], a0, 0, 0, 0);
        a0 = __builtin_amdgcn_mfma_f32_16x16x32_bf16(el, uh[0], a0, 0, 0, 0);
        a1 = __builtin_amdgcn_mfma_f32_16x16x32_bf16(eh, uh[1], a1, 0, 0, 0);
        a1 = __builtin_amdgcn_mfma_f32_16x16x32_bf16(eh, ul[1], a1, 0, 0, 0);
        a1 = __builtin_amdgcn_mfma_f32_16x16x32_bf16(el, uh[1], a1, 0, 0, 0);
#pragma unroll
        for (int r = 0; r < 4; ++r) {
            int y = (mt << 4) + (quad << 2) + r;         // C layout row
            float e0 = Et[y << 1], e1 = Et[(y << 1) + 1];
            outp[(y << 5) + col]      = a0[r] + u16a.x * e0 + u16a.y * e1;
            outp[(y << 5) + 16 + col] = a1[r] + u16b.x * e0 + u16b.y * e1;
        }
    }
}

// ---------------- K2': fused x-DFT + mix + inverse-x (UNCHANGED from R4). ----
__global__ __launch_bounds__(512) void k_mid_fused(
    const float2* __restrict__ T1, const float* __restrict__ w1r, const float* __restrict__ w1i,
    const float* __restrict__ w2r, const float* __restrict__ w2i,
    const float* __restrict__ tbuf, float2* __restrict__ U)
{
    int blk = blockIdx.x;
    int b = blk / 17, j = blk - b * 17;
    __shared__ float4 Ts4[2048];
    __shared__ float2 Xf[34 * 32];
    __shared__ float ct[128], st[128];
    int tid = threadIdx.x;
    const float4* s4 = (const float4*)(T1 + (size_t)blk * 4096);
    for (int i = tid; i < 2048; i += 512) Ts4[i] = s4[i];
    if (tid < 128) {
        float a = TWO_PI_OVER_128 * (float)tid;
        sincosf(a, &st[tid], &ct[tid]);
    }
    __syncthreads();
    for (int i = tid; i < 1008; i += 512) {
        int x = (i >> 4) + 1, cp = i & 15;
        float4 a = Ts4[(x << 4) + cp], q = Ts4[((128 - x) << 4) + cp];
        Ts4[(x << 4) + cp] = make_float4(a.x + q.x, a.y + q.y, a.z + q.z, a.w + q.w);
        Ts4[((128 - x) << 4) + cp] = make_float4(a.x - q.x, a.y - q.y, a.z - q.z, a.w - q.w);
    }
    __syncthreads();
    {
        int cp = tid & 15, g = tid >> 4;
        if (g < 16) {
            int f = g + 1;
            float sn, cs; sincosf(TWO_PI_OVER_128 * (float)f, &sn, &cs);
            float cr = cs, ci = sn;
            float P0=0,Q0=0,R0=0,T0=0,P1=0,Q1=0,R1=0,T1a=0;
            for (int x = 1; x <= 63; ++x) {
                float4 S = Ts4[(x << 4) + cp];
                float4 D = Ts4[((128 - x) << 4) + cp];
                P0 = fmaf(S.x, cr, P0); Q0 = fmaf(D.y, ci, Q0);
                R0 = fmaf(S.y, cr, R0); T0 = fmaf(D.x, ci, T0);
                P1 = fmaf(S.z, cr, P1); Q1 = fmaf(D.w, ci, Q1);
                R1 = fmaf(S.w, cr, R1); T1a = fmaf(D.z, ci, T1a);
                float nr = cr * cs - ci * sn;
                ci = fmaf(cr, sn, ci * cs);
                cr = nr;
            }
            float4 t0 = Ts4[cp], t64 = Ts4[(64 << 4) + cp];
            float sg = (f & 1) ? -1.f : 1.f;
            float b0r = t0.x + sg * t64.x, b0i = t0.y + sg * t64.y;
            float b1r = t0.z + sg * t64.z, b1i = t0.w + sg * t64.w;
            int ia = f, ib = 34 - f;
            Xf[ia * 32 + cp*2]   = make_float2(P0 + Q0 + b0r, R0 - T0 + b0i);
            Xf[ia * 32 + cp*2+1] = make_float2(P1 + Q1 + b1r, R1 - T1a + b1i);
            Xf[ib * 32 + cp*2]   = make_float2(P0 - Q0 + b0r, R0 + T0 + b0i);
            Xf[ib * 32 + cp*2+1] = make_float2(P1 - Q1 + b1r, R1 + T1a + b1i);
            if (g == 0) {
                float A0=0,B0=0,A1=0,B1=0;
                for (int x = 1; x <= 63; ++x) {
                    float4 S = Ts4[(x << 4) + cp];
                    A0 += S.x; B0 += S.y; A1 += S.z; B1 += S.w;
                }
                Xf[cp*2]   = make_float2(A0 + t0.x + t64.x, B0 + t0.y + t64.y);
                Xf[cp*2+1] = make_float2(A1 + t0.z + t64.z, B1 + t0.w + t64.w);
            }
            if (g == 8) {
                float sn2, cs2; sincosf(TWO_PI_OVER_128 * 111.f, &sn2, &cs2);
                float cr2 = cs2, ci2 = sn2;
                float p0=0,q0=0,r0=0,s0=0,p1=0,q1=0,r1=0,s1=0;
                for (int x = 1; x <= 63; ++x) {
                    float4 S = Ts4[(x << 4) + cp];
                    float4 D = Ts4[((128 - x) << 4) + cp];
                    p0 = fmaf(S.x, cr2, p0); q0 = fmaf(D.y, ci2, q0);
                    r0 = fmaf(S.y, cr2, r0); s0 = fmaf(D.x, ci2, s0);
                    p1 = fmaf(S.z, cr2, p1); q1 = fmaf(D.w, ci2, q1);
                    r1 = fmaf(S.w, cr2, r1); s1 = fmaf(D.z, ci2, s1);
                    float nr = cr2 * cs2 - ci2 * sn2;
                    ci2 = fmaf(cr2, sn2, ci2 * cs2);
                    cr2 = nr;
                }
                float c0r = t0.x - t64.x, c0i = t0.y - t64.y;
                float c1r = t0.z - t64.z, c1i = t0.w - t64.w;
                Xf[17*32 + cp*2]   = make_float2(p0 + q0 + c0r, r0 - s0 + c0i);
                Xf[17*32 + cp*2+1] = make_float2(p1 + q1 + c1r, r1 - s1 + c1i);
            }
        }
    }
    __syncthreads();
    float2* Ys = (float2*)Ts4;
    {
        int o = tid & 31, gi = tid >> 5;
#pragma unroll
        for (int t = 0; t < 3; ++t) {
            int ii = gi + (t << 4);
            if (ii < 34) {
                int irow = (ii < 17) ? ii : ii - 17;
                const float* wr = ((ii < 17) ? w1r : w2r) + ((irow * 17 + j) << 10) + o;
                const float* wi = ((ii < 17) ? w1i : w2i) + ((irow * 17 + j) << 10) + o;
                float ar = 0.f, ai = 0.f;
#pragma unroll 8
                for (int c = 0; c < 32; ++c) {
                    float2 xv = Xf[ii * 32 + c];
                    float wre = wr[c << 5], wim = wi[c << 5];
                    ar += xv.x * wre - xv.y * wim;
                    ai += xv.x * wim + xv.y * wre;
                }
                int which = (ii >= 17) ? 1 : 0;
                const float* tp = tbuf + ((which * 32 + b) * 17 + irow) * 2;
                float tr = tp[0], ti = tp[1];
                Ys[ii * 32 + o] = make_float2(ar * tr - ai * ti, ar * ti + ai * tr);
            }
        }
    }
    __syncthreads();
    {
        int o = tid & 31, g = tid >> 5;
        float yr[34], yi[34];
#pragma unroll
        for (int i = 0; i < 34; ++i) { float2 v = Ys[i * 32 + o]; yr[i] = v.x; yi[i] = v.y; }
        float2* Ub = U + ((size_t)b * 128 * 17 + j) * 32 + o;
        if (g == 0) {
            float sr = 0.f, si = 0.f;
#pragma unroll
            for (int i = 0; i < 34; ++i) { sr += yr[i]; si += yi[i]; }
            Ub[0] = make_float2(sr, si);
        }
        for (int k = 0; k < 4; ++k) {
            int x = 1 + g + (k << 4);
            if (x == 64) {
                float sr = 0.f, si = 0.f;
#pragma unroll
                for (int i = 0; i < 34; ++i) {
                    float sg2 = (i & 1) ? -1.f : 1.f;
                    sr = fmaf(sg2, yr[i], sr); si = fmaf(sg2, yi[i], si);
                }
                Ub[(size_t)64 * 544] = make_float2(sr, si);
            } else {
                float cx = ct[x], sx = st[x];
                float A1=0,A2=0,A3=0,A4=0;
                float cr = 1.f, ci = 0.f;
#pragma unroll
                for (int i = 0; i < 17; ++i) {
                    A1 = fmaf(yr[i], cr, A1); A4 = fmaf(yr[i], ci, A4);
                    A3 = fmaf(yi[i], cr, A3); A2 = fmaf(yi[i], ci, A2);
                    float nr = cr * cx - ci * sx;
                    ci = fmaf(cr, sx, ci * cx);
                    cr = nr;
                }
                int k2 = (111 * x) & 127;
                cr = ct[k2]; ci = st[k2];
#pragma unroll
                for (int i = 17; i < 34; ++i) {
                    A1 = fmaf(yr[i], cr, A1); A4 = fmaf(yr[i], ci, A4);
                    A3 = fmaf(yi[i], cr, A3); A2 = fmaf(yi[i], ci, A2);
                    float nr = cr * cx - ci * sx;
                    ci = fmaf(cr, sx, ci * cx);
                    cr = nr;
                }
                Ub[(size_t)x * 544]         = make_float2(A1 - A2, A3 + A4);
                Ub[(size_t)(128 - x) * 544] = make_float2(A1 + A2, A3 - A4);
            }
        }
    }
}

extern "C" void kernel_launch(void* const* d_in, const int* in_sizes, int n_in,
                              void* d_out, int out_size, void* d_ws, size_t ws_size,
                              hipStream_t stream)
{
    const float* x    = (const float*)d_in[0];
    const float* temb = (const float*)d_in[1];
    const float* w1r  = (const float*)d_in[2];
    const float* w1i  = (const float*)d_in[3];
    const float* w2r  = (const float*)d_in[4];
    const float* w2i  = (const float*)d_in[5];
    const float* k1r  = (const float*)d_in[6];
    const float* k1i  = (const float*)d_in[7];
    const float* k2r  = (const float*)d_in[8];
    const float* k2i  = (const float*)d_in[9];
    float* out = (float*)d_out;

    char* ws = (char*)d_ws;
    const size_t T1_B = 17825792;                        // 32*17*128*32 float2
    // layout: T1 | U | tb(8704) | Dhi(12288) | Dlo | Ehi(8192) | Elo | Et(1024)
    float2* T1 = (float2*)ws;
    float2* U  = (float2*)(ws + T1_B);
    float*  tb = (float*)(ws + 2 * T1_B);
    unsigned short* Dhi = (unsigned short*)(ws + 2 * T1_B + 8704);
    unsigned short* Dlo = (unsigned short*)(ws + 2 * T1_B + 8704 + 12288);
    unsigned short* Ehi = (unsigned short*)(ws + 2 * T1_B + 8704 + 24576);
    unsigned short* Elo = (unsigned short*)(ws + 2 * T1_B + 8704 + 24576 + 8192);
    float* Et = (float*)(ws + 2 * T1_B + 8704 + 24576 + 16384);

    k_mktab     <<<1,    256, 0, stream>>>(Dhi, Dlo, Ehi, Elo, Et);
    k_tproj     <<<32,   128, 0, stream>>>(temb, k1r, k1i, k2r, k2i, tb);
    k_fwd_y_mfma<<<1024, 256, 0, stream>>>(x, T1, Dhi, Dlo);
    k_mid_fused <<<544,  512, 0, stream>>>(T1, w1r, w1i, w2r, w2i, tb, U);
    k_inv_y_mfma<<<1024, 256, 0, stream>>>(U, out, Ehi, Elo, Et);
}